// Round 1
// baseline (1437.941 us; speedup 1.0000x reference)
//
#include <hip/hip_runtime.h>

#define T_SEQ 2048
#define DDIM  1024
#define FDIM  4096
#define NE    8
#define BM    128
#define BN    128
#define BK    64

typedef __attribute__((ext_vector_type(8))) __bf16 bf16x8;
typedef __attribute__((ext_vector_type(4))) float  f32x4;

// ---------------------------------------------------------------- async copy
__device__ __forceinline__ void gld16(const void* g, void* l) {
    __builtin_amdgcn_global_load_lds(
        (__attribute__((address_space(1))) void*)g,
        (__attribute__((address_space(3))) void*)l,
        16, 0, 0);
}

// ---------------------------------------------------------------- routing
// partial pooled sums: grid (32, 8), block 256
__global__ void kpool(const float* __restrict__ x, float* __restrict__ part) {
    int bd = blockIdx.x * 256 + threadIdx.x;     // 0..8191 = b*1024+d
    int tc = blockIdx.y;                         // 0..7
    int b = bd >> 10;
    int d = bd & 1023;
    const float* p = x + ((size_t)b * T_SEQ + (size_t)tc * 256) * DDIM + d;
    float s = 0.f;
    #pragma unroll 8
    for (int t = 0; t < 256; ++t) s += p[(size_t)t * DDIM];
    part[tc * 8192 + bd] = s;
}

// finalize routing: 1 block, 256 threads
__global__ void kroute(const float* __restrict__ part, const float* __restrict__ Wr,
                       int* __restrict__ ridx, float* __restrict__ rw) {
    __shared__ float pooled[8192];
    __shared__ float plg[256];
    __shared__ float lg[64];
    int tid = threadIdx.x;
    for (int i = tid; i < 8192; i += 256) {
        float s = 0.f;
        #pragma unroll
        for (int tc = 0; tc < 8; ++tc) s += part[tc * 8192 + i];
        pooled[i] = s * (1.0f / (float)T_SEQ);
    }
    __syncthreads();
    {
        int b = tid >> 5, e = (tid >> 2) & 7, q = tid & 3;
        float s = 0.f;
        const float* pb = pooled + b * 1024 + q * 256;
        for (int d = 0; d < 256; ++d) s += pb[d] * Wr[(q * 256 + d) * NE + e];
        plg[tid] = s;
    }
    __syncthreads();
    if (tid < 64) {
        int base = tid * 4;                      // tid = b*8+e -> plg[b*32+e*4+q]
        int b = tid >> 3, e = tid & 7;
        base = b * 32 + e * 4;
        lg[tid] = plg[base] + plg[base + 1] + plg[base + 2] + plg[base + 3];
    }
    __syncthreads();
    if (tid < 8) {
        int b = tid;
        float best = -1e30f; int bi = 0;
        #pragma unroll
        for (int e = 0; e < 8; ++e) { float v = lg[b * 8 + e]; if (v > best) { best = v; bi = e; } }
        float best2 = -1e30f; int bi2 = 0;
        #pragma unroll
        for (int e = 0; e < 8; ++e) {
            if (e == bi) continue;
            float v = lg[b * 8 + e];
            if (v > best2) { best2 = v; bi2 = e; }
        }
        float e1 = __expf(best2 - best);
        float inv = 1.0f / (1.0f + e1);
        ridx[b * 2]     = bi;
        ridx[b * 2 + 1] = bi2;
        rw[b * 2]     = inv;
        rw[b * 2 + 1] = e1 * inv;
    }
}

// ---------------------------------------------------------------- converts
// x (f32) -> bf16, 4 elements/thread
__global__ void kconvX(const float* __restrict__ in, __bf16* __restrict__ out) {
    size_t i = ((size_t)blockIdx.x * 256 + threadIdx.x) * 4;
    float4 v = *(const float4*)(in + i);
    union { __bf16 h[4]; uint2 u; } pk;
    pk.h[0] = (__bf16)v.x; pk.h[1] = (__bf16)v.y;
    pk.h[2] = (__bf16)v.z; pk.h[3] = (__bf16)v.w;
    *(uint2*)(out + i) = pk.u;
}

// transpose+convert: in (E,R,C) f32 -> out (E,C,R) bf16. grid (C/64, R/64, E)
__global__ void kconvT(const float* __restrict__ in, __bf16* __restrict__ out,
                       int R, int C) {
    __shared__ float t[64][65];
    int e  = blockIdx.z;
    int r0 = blockIdx.y * 64;
    int c0 = blockIdx.x * 64;
    int tid = threadIdx.x;
    const float* ip = in + ((size_t)e * R + r0) * C + c0;
    int tr  = tid >> 4;            // 0..15
    int tc4 = (tid & 15) * 4;      // 0..60
    #pragma unroll
    for (int j = 0; j < 4; ++j) {
        float4 v = *(const float4*)(ip + (size_t)(tr + j * 16) * C + tc4);
        t[tr + j * 16][tc4 + 0] = v.x;
        t[tr + j * 16][tc4 + 1] = v.y;
        t[tr + j * 16][tc4 + 2] = v.z;
        t[tr + j * 16][tc4 + 3] = v.w;
    }
    __syncthreads();
    __bf16* op = out + ((size_t)e * C + c0) * R + r0;
    int oc  = tid >> 2;            // 0..63 (out row = original col)
    int orb = (tid & 3) * 16;
    #pragma unroll
    for (int s = 0; s < 4; ++s) {
        int orr = orb + s * 4;
        union { __bf16 h[4]; uint2 u; } pk;
        pk.h[0] = (__bf16)t[orr + 0][oc];
        pk.h[1] = (__bf16)t[orr + 1][oc];
        pk.h[2] = (__bf16)t[orr + 2][oc];
        pk.h[3] = (__bf16)t[orr + 3][oc];
        *(uint2*)(op + (size_t)oc * R + orr) = pk.u;
    }
}

// ---------------------------------------------------------------- GEMM core
// C(128x128) += A(M x K) @ B^T(N x K), both row-major with K contiguous.
// LDS is slab-swizzled: each 16x32 MFMA fragment is one contiguous 1KB slab,
// staged by global_load_lds with per-lane global addresses; fragment ds_reads
// are base + lane*16 -> conflict-free.
__device__ __forceinline__ void mma_pass(
    const __bf16* __restrict__ A, const __bf16* __restrict__ B, int K,
    __bf16* __restrict__ As, __bf16* __restrict__ Bs,
    f32x4 (&acc)[4][4], int m0, int n0)
{
    const int tid = threadIdx.x;
    const int l   = tid & 63;
    const int w   = tid >> 6;
    const int lr  = l & 15;
    const int lq  = l >> 4;

    // slab decode for the 4 slabs this wave stages (same pattern for A and B)
    int srow[4], sk[4];
    #pragma unroll
    for (int i = 0; i < 4; ++i) {
        int s = w * 4 + i;
        srow[i] = ((s >> 3) << 6) + (((s >> 1) & 3) << 4) + lr;  // row/n in tile
        sk[i]   = ((s & 1) << 5) + (lq << 3);                    // k in tile
    }

    const int wmBlk = w >> 1;   // 0/1 -> rows [0,64) / [64,128)
    const int wnBlk = w & 1;

    for (int kt = 0; kt < K; kt += BK) {
        #pragma unroll
        for (int i = 0; i < 4; ++i) {
            int s = w * 4 + i;
            gld16(A + (size_t)(m0 + srow[i]) * K + kt + sk[i], As + s * 512 + l * 8);
            gld16(B + (size_t)(n0 + srow[i]) * K + kt + sk[i], Bs + s * 512 + l * 8);
        }
        __builtin_amdgcn_s_waitcnt(0x0f70);   // vmcnt(0); barrier below re-enforces
        __syncthreads();
        #pragma unroll
        for (int kk = 0; kk < 2; ++kk) {
            bf16x8 af[4], bfr[4];
            #pragma unroll
            for (int im = 0; im < 4; ++im)
                af[im] = *(const bf16x8*)(As + ((wmBlk * 4 + im) * 2 + kk) * 512 + l * 8);
            #pragma unroll
            for (int jn = 0; jn < 4; ++jn)
                bfr[jn] = *(const bf16x8*)(Bs + ((wnBlk * 4 + jn) * 2 + kk) * 512 + l * 8);
            #pragma unroll
            for (int im = 0; im < 4; ++im)
                #pragma unroll
                for (int jn = 0; jn < 4; ++jn)
                    acc[im][jn] = __builtin_amdgcn_mfma_f32_16x16x32_bf16(
                        af[im], bfr[jn], acc[im][jn], 0, 0, 0);
        }
        __syncthreads();
    }
}

// GEMM1: h[lp] = rw[p] * gelu(x[b] @ W1t[e]^T + b1[e]), bf16 out
__global__ __launch_bounds__(256) void gemm1_kernel(
    const __bf16* __restrict__ xbf, const __bf16* __restrict__ W1t,
    const float* __restrict__ b1, const int* __restrict__ ridx,
    const float* __restrict__ rw, __bf16* __restrict__ h, int p0)
{
    __shared__ __attribute__((aligned(16))) __bf16 As[BM * BK];
    __shared__ __attribute__((aligned(16))) __bf16 Bs[BN * BK];
    const int lp = blockIdx.z;
    const int p  = p0 + lp;
    const int b  = p >> 1;
    const int e  = ridx[p];
    const float wgt = rw[p];
    const int m0 = blockIdx.y * BM;
    const int n0 = blockIdx.x * BN;

    f32x4 acc[4][4];
    #pragma unroll
    for (int i = 0; i < 4; ++i)
        #pragma unroll
        for (int j = 0; j < 4; ++j)
            acc[i][j] = (f32x4){0.f, 0.f, 0.f, 0.f};

    mma_pass(xbf + (size_t)b * T_SEQ * DDIM, W1t + (size_t)e * FDIM * DDIM,
             DDIM, As, Bs, acc, m0, n0);

    const int l  = threadIdx.x & 63;
    const int w  = threadIdx.x >> 6;
    const int wm = (w >> 1) << 6, wn = (w & 1) << 6;
    const int lr = l & 15, lq = l >> 4;
    __bf16* hd = h + (size_t)lp * T_SEQ * FDIM;
    const float* bias = b1 + e * FDIM;
    #pragma unroll
    for (int im = 0; im < 4; ++im) {
        int row = m0 + wm + im * 16 + lq * 4;
        #pragma unroll
        for (int jn = 0; jn < 4; ++jn) {
            int col = n0 + wn + jn * 16 + lr;
            float bv = bias[col];
            #pragma unroll
            for (int r = 0; r < 4; ++r) {
                float v = acc[im][jn][r] + bv;
                v = 0.5f * v * (1.0f + erff(v * 0.70710678118654752f));
                hd[(size_t)(row + r) * FDIM + col] = (__bf16)(wgt * v);
            }
        }
    }
}

// GEMM2: out[s] = h[2s] @ W2t[e0]^T + h[2s+1] @ W2t[e1]^T + (w0 b2[e0] + w1 b2[e1])
__global__ __launch_bounds__(256) void gemm2_kernel(
    const __bf16* __restrict__ h, const __bf16* __restrict__ W2t,
    const float* __restrict__ b2, const int* __restrict__ ridx,
    const float* __restrict__ rw, float* __restrict__ out, int s0)
{
    __shared__ __attribute__((aligned(16))) __bf16 As[BM * BK];
    __shared__ __attribute__((aligned(16))) __bf16 Bs[BN * BK];
    const int ls = blockIdx.z;
    const int s  = s0 + ls;
    const int e0 = ridx[s * 2], e1 = ridx[s * 2 + 1];
    const float w0 = rw[s * 2], w1 = rw[s * 2 + 1];
    const int m0 = blockIdx.y * BM;
    const int n0 = blockIdx.x * BN;

    f32x4 acc[4][4];
    #pragma unroll
    for (int i = 0; i < 4; ++i)
        #pragma unroll
        for (int j = 0; j < 4; ++j)
            acc[i][j] = (f32x4){0.f, 0.f, 0.f, 0.f};

    mma_pass(h + (size_t)(2 * ls) * T_SEQ * FDIM, W2t + (size_t)e0 * DDIM * FDIM,
             FDIM, As, Bs, acc, m0, n0);
    mma_pass(h + (size_t)(2 * ls + 1) * T_SEQ * FDIM, W2t + (size_t)e1 * DDIM * FDIM,
             FDIM, As, Bs, acc, m0, n0);

    const int l  = threadIdx.x & 63;
    const int w  = threadIdx.x >> 6;
    const int wm = (w >> 1) << 6, wn = (w & 1) << 6;
    const int lr = l & 15, lq = l >> 4;
    float* od = out + (size_t)s * T_SEQ * DDIM;
    const float* bb0 = b2 + e0 * DDIM;
    const float* bb1 = b2 + e1 * DDIM;
    #pragma unroll
    for (int im = 0; im < 4; ++im) {
        int row = m0 + wm + im * 16 + lq * 4;
        #pragma unroll
        for (int jn = 0; jn < 4; ++jn) {
            int col = n0 + wn + jn * 16 + lr;
            float bv = w0 * bb0[col] + w1 * bb1[col];
            #pragma unroll
            for (int r = 0; r < 4; ++r)
                od[(size_t)(row + r) * DDIM + col] = acc[im][jn][r] + bv;
        }
    }
}

// ---------------------------------------------------------------- launch
extern "C" void kernel_launch(void* const* d_in, const int* in_sizes, int n_in,
                              void* d_out, int out_size, void* d_ws, size_t ws_size,
                              hipStream_t stream) {
    const float* x  = (const float*)d_in[0];
    const float* Wr = (const float*)d_in[1];
    const float* W1 = (const float*)d_in[2];
    const float* b1 = (const float*)d_in[3];
    const float* W2 = (const float*)d_in[4];
    const float* b2 = (const float*)d_in[5];
    float* out = (float*)d_out;
    char*  ws  = (char*)d_ws;

    // workspace layout (bytes)
    int*    ridx = (int*)(ws + 0);                              // 16 ints
    float*  rw   = (float*)(ws + 64);                           // 16 floats
    float*  part = (float*)(ws + 1024);                         // 8*8192 f32 = 256KB
    __bf16* xbf  = (__bf16*)(ws + ((size_t)1  << 20));          // 32MB
    __bf16* W1t  = (__bf16*)(ws + ((size_t)33 << 20));          // 64MB  (E,F,D)
    __bf16* W2t  = (__bf16*)(ws + ((size_t)97 << 20));          // 64MB  (E,D,F)
    __bf16* hbuf = (__bf16*)(ws + ((size_t)161 << 20));         // up to 256MB

    kpool <<<dim3(32, 8), 256, 0, stream>>>(x, part);
    kroute<<<1, 256, 0, stream>>>(part, Wr, ridx, rw);
    kconvX<<<16384, 256, 0, stream>>>(x, xbf);
    kconvT<<<dim3(FDIM / 64, DDIM / 64, NE), 256, 0, stream>>>(W1, W1t, DDIM, FDIM);
    kconvT<<<dim3(DDIM / 64, FDIM / 64, NE), 256, 0, stream>>>(W2, W2t, FDIM, DDIM);

    // chunk samples by available h space (32MB per sample = 2 pairs x 16MB)
    const size_t h_per_sample = (size_t)2 * T_SEQ * FDIM * sizeof(__bf16);
    size_t hcap = (ws_size > ((size_t)161 << 20)) ? ws_size - ((size_t)161 << 20) : 0;
    int csmax = (int)(hcap / h_per_sample);
    if (csmax < 1) csmax = 1;
    if (csmax > 8) csmax = 8;

    for (int smp0 = 0; smp0 < 8; smp0 += csmax) {
        int cs = (8 - smp0 < csmax) ? (8 - smp0) : csmax;
        gemm1_kernel<<<dim3(FDIM / BN, T_SEQ / BM, 2 * cs), 256, 0, stream>>>(
            xbf, W1t, b1, ridx, rw, hbuf, smp0 * 2);
        gemm2_kernel<<<dim3(DDIM / BN, T_SEQ / BM, cs), 256, 0, stream>>>(
            hbuf, W2t, b2, ridx, rw, out, smp0);
    }
}